// Round 1
// baseline (586.212 us; speedup 1.0000x reference)
//
#include <hip/hip_runtime.h>
#include <math.h>

#define EPSV 1e-5f

// ---------------------------------------------------------------------------
// K1: Y[r][n] = sum_c X[r][c] * W[c][n] + bias[n]   (C=256, N=64)
// 64 rows per block, 256 threads, 4x4 register tile, 16-wide K chunks in LDS.
// ---------------------------------------------------------------------------
__global__ __launch_bounds__(256) void gemm_k256_n64(
    const float* __restrict__ X, const float* __restrict__ W,
    const float* __restrict__ bias, float* __restrict__ Y)
{
    __shared__ float Xc[16][64];   // [c_local][row]
    __shared__ float Wc[16][64];   // [c_local][n]
    const int t = threadIdx.x;
    const long r0 = (long)blockIdx.x * 64;
    const int tr = t >> 4;          // 0..15
    const int tc = t & 15;          // 0..15

    float4 bv = *(const float4*)(bias + tc * 4);
    float acc[4][4];
#pragma unroll
    for (int i = 0; i < 4; ++i) { acc[i][0] = bv.x; acc[i][1] = bv.y; acc[i][2] = bv.z; acc[i][3] = bv.w; }

    const int lr = t >> 2;          // 0..63 (row for X load)
    const int lc = (t & 3) * 4;     // 0,4,8,12
    const int wl = t >> 4;          // 0..15 (c_local for W load)
    const int wj = (t & 15) * 4;

    for (int c0 = 0; c0 < 256; c0 += 16) {
        float4 xv = *(const float4*)(X + (r0 + lr) * 256 + c0 + lc);
        float4 wv = *(const float4*)(W + (long)(c0 + wl) * 64 + wj);
        Xc[lc + 0][lr] = xv.x; Xc[lc + 1][lr] = xv.y; Xc[lc + 2][lr] = xv.z; Xc[lc + 3][lr] = xv.w;
        *(float4*)&Wc[wl][wj] = wv;
        __syncthreads();
#pragma unroll
        for (int cl = 0; cl < 16; ++cl) {
            float4 a = *(float4*)&Xc[cl][tr * 4];
            float4 b = *(float4*)&Wc[cl][tc * 4];
            acc[0][0] += a.x * b.x; acc[0][1] += a.x * b.y; acc[0][2] += a.x * b.z; acc[0][3] += a.x * b.w;
            acc[1][0] += a.y * b.x; acc[1][1] += a.y * b.y; acc[1][2] += a.y * b.z; acc[1][3] += a.y * b.w;
            acc[2][0] += a.z * b.x; acc[2][1] += a.z * b.y; acc[2][2] += a.z * b.z; acc[2][3] += a.z * b.w;
            acc[3][0] += a.w * b.x; acc[3][1] += a.w * b.y; acc[3][2] += a.w * b.z; acc[3][3] += a.w * b.w;
        }
        __syncthreads();
    }
#pragma unroll
    for (int i = 0; i < 4; ++i) {
        float4 o = make_float4(acc[i][0], acc[i][1], acc[i][2], acc[i][3]);
        *(float4*)(Y + (r0 + tr * 4 + i) * 64 + tc * 4) = o;
    }
}

// ---------------------------------------------------------------------------
// K2: S[b][n][c] = sum_p Yn[b*P+p][n] * X[b*P+p][c]  (N=64, C=256 tiled by 64)
// grid (C/64, B); 256 threads, 4x4 tile, K chunks of 16 pixels.
// ---------------------------------------------------------------------------
__global__ __launch_bounds__(256) void corr_nt(
    const float* __restrict__ Yn, const float* __restrict__ X,
    float* __restrict__ S, int P)
{
    __shared__ float A[16 * 64];    // [p][n]
    __shared__ float Bt[16 * 64];   // [p][c_local]
    const int t = threadIdx.x;
    const int b = blockIdx.y;
    const int c0 = blockIdx.x * 64;
    const int lp = t >> 4;          // 0..15
    const int lj = (t & 15) * 4;
    const int tn = t >> 4, tc = t & 15;

    float acc[4][4] = {};
    for (int p0 = 0; p0 < P; p0 += 16) {
        long rb = (long)(b * P + p0 + lp);
        *(float4*)&A[lp * 64 + lj]  = *(const float4*)(Yn + rb * 64 + lj);
        *(float4*)&Bt[lp * 64 + lj] = *(const float4*)(X + rb * 256 + c0 + lj);
        __syncthreads();
#pragma unroll
        for (int p = 0; p < 16; ++p) {
            float4 a = *(float4*)&A[p * 64 + tn * 4];
            float4 b4 = *(float4*)&Bt[p * 64 + tc * 4];
            acc[0][0] += a.x * b4.x; acc[0][1] += a.x * b4.y; acc[0][2] += a.x * b4.z; acc[0][3] += a.x * b4.w;
            acc[1][0] += a.y * b4.x; acc[1][1] += a.y * b4.y; acc[1][2] += a.y * b4.z; acc[1][3] += a.y * b4.w;
            acc[2][0] += a.z * b4.x; acc[2][1] += a.z * b4.y; acc[2][2] += a.z * b4.z; acc[2][3] += a.z * b4.w;
            acc[3][0] += a.w * b4.x; acc[3][1] += a.w * b4.y; acc[3][2] += a.w * b4.z; acc[3][3] += a.w * b4.w;
        }
        __syncthreads();
    }
#pragma unroll
    for (int i = 0; i < 4; ++i) {
        float4 o = make_float4(acc[i][0], acc[i][1], acc[i][2], acc[i][3]);
        *(float4*)(S + ((long)(b * 64 + tn * 4 + i)) * 256 + c0 + tc * 4) = o;
    }
}

// ---------------------------------------------------------------------------
// K3: dy[b][n][j] = sum_c kern[b][n][c]*Wdyn[c][j] + bdyn[j]  (j<67, stride 68)
// ---------------------------------------------------------------------------
__global__ __launch_bounds__(256) void dy_kernel(
    const float* __restrict__ kern, const float* __restrict__ Wdyn,
    const float* __restrict__ bdyn, float* __restrict__ dy)
{
    const int b = blockIdx.x, t = threadIdx.x;
    for (int idx = t; idx < 64 * 67; idx += 256) {
        int n = idx / 67, j = idx % 67;
        const float* kr = kern + ((long)(b * 64 + n)) * 256;
        float acc = bdyn[j];
        for (int c = 0; c < 256; ++c) acc += kr[c] * Wdyn[c * 67 + j];
        dy[((long)(b * 64 + n)) * 68 + j] = acc;
    }
}

// ---------------------------------------------------------------------------
// K4: depth conv + point GEMM: point[b][n][c] = sum_m wp[n][m]*relu(conv3(v[m],c))
// one block per batch; thread t owns channel column c=t.
// ---------------------------------------------------------------------------
__global__ __launch_bounds__(256) void point_kernel(
    const float* __restrict__ dy, const float* __restrict__ v,
    float* __restrict__ point)
{
    __shared__ float wp[64][64];
    __shared__ float wd[64][4];
    const int b = blockIdx.x, t = threadIdx.x;
#pragma unroll
    for (int i = 0; i < 16; ++i) {
        int idx = t + i * 256;
        int n = idx >> 6, m = idx & 63;
        wp[n][m] = dy[((long)(b * 64 + n)) * 68 + 3 + m];
    }
    if (t < 64) {
        long o = ((long)(b * 64 + t)) * 68;
        wd[t][0] = dy[o + 0]; wd[t][1] = dy[o + 1]; wd[t][2] = dy[o + 2];
    }
    __syncthreads();
    const int c = t;
    float dcol[64];
#pragma unroll
    for (int m = 0; m < 64; ++m) {
        const float* vr = v + ((long)(b * 64 + m)) * 256;
        float vm = (c > 0)   ? vr[c - 1] : 0.f;
        float v0 = vr[c];
        float vp = (c < 255) ? vr[c + 1] : 0.f;
        float d = wd[m][0] * vm + wd[m][1] * v0 + wd[m][2] * vp;
        dcol[m] = fmaxf(d, 0.f);
    }
    for (int n = 0; n < 64; ++n) {
        float acc = 0.f;
#pragma unroll
        for (int m4 = 0; m4 < 16; ++m4) {
            float4 w = *(float4*)&wp[n][m4 * 4];
            acc += w.x * dcol[m4 * 4 + 0] + w.y * dcol[m4 * 4 + 1]
                 + w.z * dcol[m4 * 4 + 2] + w.w * dcol[m4 * 4 + 3];
        }
        point[((long)(b * 64 + n)) * 256 + c] = acc;
    }
}

// ---------------------------------------------------------------------------
// K5: layernorm over c of point -> kx (with g_norm, b_norm). one block/batch.
// ---------------------------------------------------------------------------
__global__ __launch_bounds__(256) void ln_kernel(
    const float* __restrict__ point, const float* __restrict__ g,
    const float* __restrict__ bta, float* __restrict__ kx)
{
    __shared__ float ps[64][4], ps2[64][4];
    __shared__ float mu[64], rs[64];
    const int b = blockIdx.x, t = threadIdx.x;
    const int n = t >> 2, q = t & 3;
    const float* pr = point + ((long)(b * 64 + n)) * 256 + q * 64;
    float s = 0.f, s2 = 0.f;
    for (int c = 0; c < 64; ++c) { float v = pr[c]; s += v; s2 += v * v; }
    ps[n][q] = s; ps2[n][q] = s2;
    __syncthreads();
    if (t < 64) {
        float ss  = ps[t][0] + ps[t][1] + ps[t][2] + ps[t][3];
        float ss2 = ps2[t][0] + ps2[t][1] + ps2[t][2] + ps2[t][3];
        float m = ss * (1.f / 256.f);
        float var = ss2 * (1.f / 256.f) - m * m;
        mu[t] = m; rs[t] = rsqrtf(var + EPSV);
    }
    __syncthreads();
    const int c = t;
    const float gc = g[c], bc = bta[c];
    for (int n2 = 0; n2 < 64; ++n2) {
        long off = ((long)(b * 64 + n2)) * 256 + c;
        kx[off] = (point[off] - mu[n2]) * rs[n2] * gc + bc;
    }
}

// ---------------------------------------------------------------------------
// K6: proto[n] = sum_c kx[n][c]*Wp[c] + bp ; tem[c] = sigmoid(sum_n proto[n]*kx[n][c])
// ---------------------------------------------------------------------------
__global__ __launch_bounds__(256) void tem_kernel(
    const float* __restrict__ kx, const float* __restrict__ Wp,
    const float* __restrict__ bp, float* __restrict__ tem)
{
    __shared__ float ps[64][4];
    __shared__ float proto[64];
    const int b = blockIdx.x, t = threadIdx.x;
    const int n = t >> 2, q = t & 3;
    const float* kr = kx + ((long)(b * 64 + n)) * 256 + q * 64;
    const float* wr = Wp + q * 64;
    float s = 0.f;
    for (int c = 0; c < 64; ++c) s += kr[c] * wr[c];
    ps[n][q] = s;
    __syncthreads();
    if (t < 64) proto[t] = ps[t][0] + ps[t][1] + ps[t][2] + ps[t][3] + bp[0];
    __syncthreads();
    const int c = t;
    float s2 = 0.f;
    for (int n2 = 0; n2 < 64; ++n2) s2 += proto[n2] * kx[((long)(b * 64 + n2)) * 256 + c];
    tem[b * 256 + c] = 1.f / (1.f + expf(-s2));
}

// ---------------------------------------------------------------------------
// K7: x_corr = x_n @ kx, *tem, LN(g_ln,b_ln), relu, + x_feat -> out
// grid (P/16, B); 16 pixels per block; thread (p = t>>4, 4 channels x 4 chunks)
// ---------------------------------------------------------------------------
__global__ __launch_bounds__(256) void final_kernel(
    const float* __restrict__ xn, const float* __restrict__ kx,
    const float* __restrict__ tem, const float* __restrict__ xf,
    const float* __restrict__ g, const float* __restrict__ bt,
    float* __restrict__ out)
{
    __shared__ float kxch[64][64];
    __shared__ float xnt[16][64];
    __shared__ float rps[16][16];
    __shared__ float rps2[16][16];
    __shared__ float mus[16], rss[16];
    const int t = threadIdx.x;
    const int b = blockIdx.y;
    const int pg = blockIdx.x;
    const int p = t >> 4;
    const int q = t & 15;
    const int cl = q * 4;

    *(float4*)&xnt[p][cl] = *(const float4*)(xn + ((long)(b * 1024 + pg * 16 + p)) * 64 + cl);

    float4 xcv[4];
    float s = 0.f, s2 = 0.f;
    for (int cc = 0; cc < 4; ++cc) {
        __syncthreads();
#pragma unroll
        for (int i = 0; i < 4; ++i) {
            int f = t + i * 256;
            int n = f >> 4;
            int j = (f & 15) * 4;
            *(float4*)&kxch[n][j] = *(const float4*)(kx + ((long)(b * 64 + n)) * 256 + cc * 64 + j);
        }
        __syncthreads();
        float4 a = {0.f, 0.f, 0.f, 0.f};
#pragma unroll
        for (int n = 0; n < 64; ++n) {
            float xv = xnt[p][n];
            float4 kv = *(float4*)&kxch[n][cl];
            a.x += xv * kv.x; a.y += xv * kv.y; a.z += xv * kv.z; a.w += xv * kv.w;
        }
        int cb = cc * 64 + cl;
        a.x *= tem[b * 256 + cb + 0];
        a.y *= tem[b * 256 + cb + 1];
        a.z *= tem[b * 256 + cb + 2];
        a.w *= tem[b * 256 + cb + 3];
        xcv[cc] = a;
        s  += a.x + a.y + a.z + a.w;
        s2 += a.x * a.x + a.y * a.y + a.z * a.z + a.w * a.w;
    }
    rps[p][q] = s; rps2[p][q] = s2;
    __syncthreads();
    if (t < 16) {
        float ss = 0.f, ss2 = 0.f;
        for (int i = 0; i < 16; ++i) { ss += rps[t][i]; ss2 += rps2[t][i]; }
        float m = ss * (1.f / 256.f);
        float var = ss2 * (1.f / 256.f) - m * m;
        mus[t] = m; rss[t] = rsqrtf(var + EPSV);
    }
    __syncthreads();
    const float m = mus[p], r = rss[p];
    const long grow = ((long)(b * 1024 + pg * 16 + p)) * 256;
#pragma unroll
    for (int cc = 0; cc < 4; ++cc) {
        int cb = cc * 64 + cl;
        float4 xfv = *(const float4*)(xf + grow + cb);
        float4 a = xcv[cc];
        float4 o;
        o.x = xfv.x + fmaxf((a.x - m) * r * g[cb + 0] + bt[cb + 0], 0.f);
        o.y = xfv.y + fmaxf((a.y - m) * r * g[cb + 1] + bt[cb + 1], 0.f);
        o.z = xfv.z + fmaxf((a.z - m) * r * g[cb + 2] + bt[cb + 2], 0.f);
        o.w = xfv.w + fmaxf((a.w - m) * r * g[cb + 3] + bt[cb + 3], 0.f);
        *(float4*)(out + grow + cb) = o;
    }
}

extern "C" void kernel_launch(void* const* d_in, const int* in_sizes, int n_in,
                              void* d_out, int out_size, void* d_ws, size_t ws_size,
                              hipStream_t stream)
{
    (void)in_sizes; (void)n_in; (void)out_size; (void)ws_size;
    const float* x_feat = (const float*)d_in[0];
    const float* z_feat = (const float*)d_in[1];
    const float* Wz     = (const float*)d_in[2];
    const float* bz     = (const float*)d_in[3];
    const float* Wx     = (const float*)d_in[4];
    const float* bx     = (const float*)d_in[5];
    const float* Wdyn   = (const float*)d_in[6];
    const float* bdyn   = (const float*)d_in[7];
    const float* g_norm = (const float*)d_in[8];
    const float* b_norm = (const float*)d_in[9];
    const float* Wp     = (const float*)d_in[10];
    const float* bp     = (const float*)d_in[11];
    const float* g_ln   = (const float*)d_in[12];
    const float* b_ln   = (const float*)d_in[13];
    float* out = (float*)d_out;

    float* ws   = (float*)d_ws;
    float* xn   = ws;                 // 64*1024*64 = 4,194,304
    float* zc   = xn + 4194304;       // 64*256*64  = 1,048,576 (reused as 'point')
    float* kern = zc + 1048576;       // 64*64*256  = 1,048,576
    float* kxr  = kern + 1048576;     // 64*64*256  = 1,048,576
    float* dyb  = kxr + 1048576;      // 64*64*68   =   278,528
    float* kx   = dyb + 278528;       // 64*64*256  = 1,048,576
    float* temb = kx + 1048576;       // 64*256     =    16,384
    float* point = zc;                // alias: zc dead after corr_nt(z)

    // x path
    gemm_k256_n64<<<1024, 256, 0, stream>>>(x_feat, Wx, bx, xn);
    // z path
    gemm_k256_n64<<<256, 256, 0, stream>>>(z_feat, Wz, bz, zc);
    corr_nt<<<dim3(4, 64), 256, 0, stream>>>(zc, z_feat, kern, 256);
    corr_nt<<<dim3(4, 64), 256, 0, stream>>>(xn, x_feat, kxr, 1024);
    // dysep conv attention
    dy_kernel<<<64, 256, 0, stream>>>(kern, Wdyn, bdyn, dyb);
    point_kernel<<<64, 256, 0, stream>>>(dyb, kxr, point);
    ln_kernel<<<64, 256, 0, stream>>>(point, g_norm, b_norm, kx);
    tem_kernel<<<64, 256, 0, stream>>>(kx, Wp, bp, temb);
    // fused correlation + gating + layernorm + relu + residual
    final_kernel<<<dim3(64, 64), 256, 0, stream>>>(xn, kx, temb, x_feat, g_ln, b_ln, out);
}

// Round 2
// 314.733 us; speedup vs baseline: 1.8626x; 1.8626x over previous
//
#include <hip/hip_runtime.h>
#include <math.h>

#define EPSV 1e-5f

// ---------------------------------------------------------------------------
// K1: combined projection GEMMs. blocks 0..1023: x-path, 1024..1279: z-path.
// Y[r][n] = sum_c X[r][c]*W[c][n] + bias[n]  (C=256, N=64), register-prefetch
// double buffer so the next chunk's global loads fly during compute.
// ---------------------------------------------------------------------------
__global__ __launch_bounds__(256) void gemm_all(
    const float* __restrict__ Xx, const float* __restrict__ Wxp,
    const float* __restrict__ bxp, float* __restrict__ Yx,
    const float* __restrict__ Xz, const float* __restrict__ Wzp,
    const float* __restrict__ bzp, float* __restrict__ Yz)
{
    __shared__ float Xc[16][64];
    __shared__ float Wc[16][64];
    const int t = threadIdx.x;
    const float *X, *W, *bias; float* Y; long r0;
    if (blockIdx.x < 1024) { X = Xx; W = Wxp; bias = bxp; Y = Yx; r0 = (long)blockIdx.x * 64; }
    else                   { X = Xz; W = Wzp; bias = bzp; Y = Yz; r0 = (long)(blockIdx.x - 1024) * 64; }

    const int tr = t >> 4, tc = t & 15;
    float4 bv = *(const float4*)(bias + tc * 4);
    float acc[4][4];
#pragma unroll
    for (int i = 0; i < 4; ++i) { acc[i][0]=bv.x; acc[i][1]=bv.y; acc[i][2]=bv.z; acc[i][3]=bv.w; }

    const int lr = t >> 2, lc = (t & 3) * 4;
    const int wl = t >> 4, wj = (t & 15) * 4;
    float4 xv = *(const float4*)(X + (r0 + lr) * 256 + lc);
    float4 wv = *(const float4*)(W + (long)wl * 64 + wj);

    for (int c0 = 0; c0 < 256; c0 += 16) {
        Xc[lc + 0][lr] = xv.x; Xc[lc + 1][lr] = xv.y; Xc[lc + 2][lr] = xv.z; Xc[lc + 3][lr] = xv.w;
        *(float4*)&Wc[wl][wj] = wv;
        __syncthreads();
        if (c0 + 16 < 256) {
            xv = *(const float4*)(X + (r0 + lr) * 256 + c0 + 16 + lc);
            wv = *(const float4*)(W + (long)(c0 + 16 + wl) * 64 + wj);
        }
#pragma unroll
        for (int cl = 0; cl < 16; ++cl) {
            float4 a = *(float4*)&Xc[cl][tr * 4];
            float4 b = *(float4*)&Wc[cl][tc * 4];
            acc[0][0] += a.x * b.x; acc[0][1] += a.x * b.y; acc[0][2] += a.x * b.z; acc[0][3] += a.x * b.w;
            acc[1][0] += a.y * b.x; acc[1][1] += a.y * b.y; acc[1][2] += a.y * b.z; acc[1][3] += a.y * b.w;
            acc[2][0] += a.z * b.x; acc[2][1] += a.z * b.y; acc[2][2] += a.z * b.z; acc[2][3] += a.z * b.w;
            acc[3][0] += a.w * b.x; acc[3][1] += a.w * b.y; acc[3][2] += a.w * b.z; acc[3][3] += a.w * b.w;
        }
        __syncthreads();
    }
#pragma unroll
    for (int i = 0; i < 4; ++i) {
        float4 o = make_float4(acc[i][0], acc[i][1], acc[i][2], acc[i][3]);
        *(float4*)(Y + (r0 + tr * 4 + i) * 64 + tc * 4) = o;
    }
}

// ---------------------------------------------------------------------------
// K2: combined correlations. blockIdx.y<64: x-path (P=1024), else z (P=256).
// S[b][n][c] = sum_p Yn[b*P+p][n] * X[b*P+p][c], with prefetch.
// ---------------------------------------------------------------------------
__global__ __launch_bounds__(256) void corr_all(
    const float* __restrict__ xn, const float* __restrict__ xf,
    float* __restrict__ kxr, const float* __restrict__ zc,
    const float* __restrict__ zf, float* __restrict__ kern)
{
    __shared__ float A[16 * 64];
    __shared__ float Bt[16 * 64];
    const int t = threadIdx.x;
    const float *Yn, *X; float* S; int b, P;
    if (blockIdx.y < 64) { b = blockIdx.y;      Yn = xn; X = xf; S = kxr;  P = 1024; }
    else                 { b = blockIdx.y - 64; Yn = zc; X = zf; S = kern; P = 256;  }
    const int c0 = blockIdx.x * 64;
    const int lp = t >> 4, lj = (t & 15) * 4;
    const int tn = t >> 4, tc = t & 15;

    float acc[4][4] = {};
    long rb = (long)b * P + lp;
    float4 av = *(const float4*)(Yn + rb * 64 + lj);
    float4 bv = *(const float4*)(X + rb * 256 + c0 + lj);

    for (int p0 = 0; p0 < P; p0 += 16) {
        *(float4*)&A[lp * 64 + lj] = av;
        *(float4*)&Bt[lp * 64 + lj] = bv;
        __syncthreads();
        if (p0 + 16 < P) {
            long rb2 = (long)b * P + p0 + 16 + lp;
            av = *(const float4*)(Yn + rb2 * 64 + lj);
            bv = *(const float4*)(X + rb2 * 256 + c0 + lj);
        }
#pragma unroll
        for (int p = 0; p < 16; ++p) {
            float4 a = *(float4*)&A[p * 64 + tn * 4];
            float4 b4 = *(float4*)&Bt[p * 64 + tc * 4];
            acc[0][0] += a.x * b4.x; acc[0][1] += a.x * b4.y; acc[0][2] += a.x * b4.z; acc[0][3] += a.x * b4.w;
            acc[1][0] += a.y * b4.x; acc[1][1] += a.y * b4.y; acc[1][2] += a.y * b4.z; acc[1][3] += a.y * b4.w;
            acc[2][0] += a.z * b4.x; acc[2][1] += a.z * b4.y; acc[2][2] += a.z * b4.z; acc[2][3] += a.z * b4.w;
            acc[3][0] += a.w * b4.x; acc[3][1] += a.w * b4.y; acc[3][2] += a.w * b4.z; acc[3][3] += a.w * b4.w;
        }
        __syncthreads();
    }
#pragma unroll
    for (int i = 0; i < 4; ++i) {
        float4 o = make_float4(acc[i][0], acc[i][1], acc[i][2], acc[i][3]);
        *(float4*)(S + ((long)(b * 64 + tn * 4 + i)) * 256 + c0 + tc * 4) = o;
    }
}

// ---------------------------------------------------------------------------
// K3: fused per-batch chain: dy-GEMM (point cols, tiled, into LDS wp) +
// depth cols (wd) + depth conv + point GEMM + LayerNorm + proto/tem.
// pointbuf (global scratch) holds pre-LN point matrix for cross-thread stats.
// ---------------------------------------------------------------------------
__global__ __launch_bounds__(256) void pointln_tem(
    const float* __restrict__ kern, const float* __restrict__ Wdyn,
    const float* __restrict__ bdyn, const float* __restrict__ v,
    const float* __restrict__ g, const float* __restrict__ bta,
    const float* __restrict__ Wp, const float* __restrict__ bp,
    float* __restrict__ pointbuf, float* __restrict__ kx,
    float* __restrict__ tem)
{
    __shared__ float wp[64][64];
    __shared__ float Ac[16][64];
    __shared__ float Wc[16][64];
    __shared__ float wd[64][4];
    __shared__ float red1[64][4], red2[64][4];
    __shared__ float mu[64], rr[64], proto[64];
    const int b = blockIdx.x, t = threadIdx.x;
    const int tr = t >> 4, tc = t & 15;

    // ---- dy point-part GEMM: wp[n][m] = sum_c kern[b,n,c]*Wdyn[c,3+m] + bdyn[3+m]
    {
        float acc[4][4];
#pragma unroll
        for (int j = 0; j < 4; ++j) {
            float bj = bdyn[3 + tc * 4 + j];
            acc[0][j] = bj; acc[1][j] = bj; acc[2][j] = bj; acc[3][j] = bj;
        }
        const int lr = t >> 2, lc = (t & 3) * 4;
        const int wl = t >> 4, wj = (t & 15) * 4;
        float4 av = *(const float4*)(kern + ((long)(b * 64 + lr)) * 256 + lc);
        float w0 = Wdyn[wl * 67 + 3 + wj + 0];
        float w1 = Wdyn[wl * 67 + 3 + wj + 1];
        float w2 = Wdyn[wl * 67 + 3 + wj + 2];
        float w3 = Wdyn[wl * 67 + 3 + wj + 3];
        for (int c0 = 0; c0 < 256; c0 += 16) {
            Ac[lc + 0][lr] = av.x; Ac[lc + 1][lr] = av.y; Ac[lc + 2][lr] = av.z; Ac[lc + 3][lr] = av.w;
            Wc[wl][wj + 0] = w0; Wc[wl][wj + 1] = w1; Wc[wl][wj + 2] = w2; Wc[wl][wj + 3] = w3;
            __syncthreads();
            if (c0 + 16 < 256) {
                av = *(const float4*)(kern + ((long)(b * 64 + lr)) * 256 + c0 + 16 + lc);
                w0 = Wdyn[(c0 + 16 + wl) * 67 + 3 + wj + 0];
                w1 = Wdyn[(c0 + 16 + wl) * 67 + 3 + wj + 1];
                w2 = Wdyn[(c0 + 16 + wl) * 67 + 3 + wj + 2];
                w3 = Wdyn[(c0 + 16 + wl) * 67 + 3 + wj + 3];
            }
#pragma unroll
            for (int cl = 0; cl < 16; ++cl) {
                float4 a = *(float4*)&Ac[cl][tr * 4];
                float4 w = *(float4*)&Wc[cl][tc * 4];
                acc[0][0] += a.x * w.x; acc[0][1] += a.x * w.y; acc[0][2] += a.x * w.z; acc[0][3] += a.x * w.w;
                acc[1][0] += a.y * w.x; acc[1][1] += a.y * w.y; acc[1][2] += a.y * w.z; acc[1][3] += a.y * w.w;
                acc[2][0] += a.z * w.x; acc[2][1] += a.z * w.y; acc[2][2] += a.z * w.z; acc[2][3] += a.z * w.w;
                acc[3][0] += a.w * w.x; acc[3][1] += a.w * w.y; acc[3][2] += a.w * w.z; acc[3][3] += a.w * w.w;
            }
            __syncthreads();
        }
#pragma unroll
        for (int i = 0; i < 4; ++i)
            *(float4*)&wp[tr * 4 + i][tc * 4] = make_float4(acc[i][0], acc[i][1], acc[i][2], acc[i][3]);
    }
    // ---- depth cols: wd[n][j] = sum_c kern[b,n,c]*Wdyn[c,j] + bdyn[j], j<3
    if (t < 192) {
        int n = t / 3, j = t - n * 3;
        const float* kr = kern + ((long)(b * 64 + n)) * 256;
        float a0 = 0.f, a1 = 0.f, a2 = 0.f, a3 = 0.f;
        for (int c = 0; c < 256; c += 4) {
            a0 += kr[c + 0] * Wdyn[(c + 0) * 67 + j];
            a1 += kr[c + 1] * Wdyn[(c + 1) * 67 + j];
            a2 += kr[c + 2] * Wdyn[(c + 2) * 67 + j];
            a3 += kr[c + 3] * Wdyn[(c + 3) * 67 + j];
        }
        wd[n][j] = a0 + a1 + a2 + a3 + bdyn[j];
    }
    __syncthreads();

    // ---- depth conv (relu) per channel column c = t
    const int c = t;
    float dcol[64];
#pragma unroll
    for (int m = 0; m < 64; ++m) {
        const float* vr = v + ((long)(b * 64 + m)) * 256;
        float vm = (c > 0)   ? vr[c - 1] : 0.f;
        float v0 = vr[c];
        float vp = (c < 255) ? vr[c + 1] : 0.f;
        float d = wd[m][0] * vm + wd[m][1] * v0 + wd[m][2] * vp;
        dcol[m] = fmaxf(d, 0.f);
    }
    // ---- point GEMM: pointbuf[n][c] = sum_m wp[n][m]*dcol[m]
#pragma unroll 4
    for (int n = 0; n < 64; ++n) {
        float a = 0.f;
#pragma unroll
        for (int m4 = 0; m4 < 16; ++m4) {
            float4 w = *(float4*)&wp[n][m4 * 4];
            a += w.x * dcol[m4 * 4 + 0] + w.y * dcol[m4 * 4 + 1]
               + w.z * dcol[m4 * 4 + 2] + w.w * dcol[m4 * 4 + 3];
        }
        pointbuf[((long)(b * 64 + n)) * 256 + c] = a;
    }
    __syncthreads();
    // ---- LN stats
    {
        int n = t >> 2, q = t & 3;
        const float* pr = pointbuf + ((long)(b * 64 + n)) * 256 + q * 64;
        float s = 0.f, s2 = 0.f;
        for (int k = 0; k < 64; ++k) { float x = pr[k]; s += x; s2 += x * x; }
        red1[n][q] = s; red2[n][q] = s2;
    }
    __syncthreads();
    if (t < 64) {
        float s  = red1[t][0] + red1[t][1] + red1[t][2] + red1[t][3];
        float s2 = red2[t][0] + red2[t][1] + red2[t][2] + red2[t][3];
        float m = s * (1.f / 256.f);
        mu[t] = m; rr[t] = rsqrtf(s2 * (1.f / 256.f) - m * m + EPSV);
    }
    __syncthreads();
    // ---- normalize + write kx
    {
        float gc = g[c], bc = bta[c];
#pragma unroll 4
        for (int n = 0; n < 64; ++n) {
            long off = ((long)(b * 64 + n)) * 256 + c;
            kx[off] = (pointbuf[off] - mu[n]) * rr[n] * gc + bc;
        }
    }
    __syncthreads();
    // ---- proto[n] = sum_c kx[n][c]*Wp[c] + bp
    {
        int n = t >> 2, q = t & 3;
        const float* kr = kx + ((long)(b * 64 + n)) * 256 + q * 64;
        const float* wr = Wp + q * 64;
        float s = 0.f;
        for (int k = 0; k < 64; ++k) s += kr[k] * wr[k];
        red1[n][q] = s;
    }
    __syncthreads();
    if (t < 64) proto[t] = red1[t][0] + red1[t][1] + red1[t][2] + red1[t][3] + bp[0];
    __syncthreads();
    // ---- tem[c] = sigmoid(sum_n proto[n]*kx[n][c])
    {
        float s = 0.f;
#pragma unroll 4
        for (int n = 0; n < 64; ++n) s += proto[n] * kx[((long)(b * 64 + n)) * 256 + c];
        tem[b * 256 + c] = 1.f / (1.f + expf(-s));
    }
}

// ---------------------------------------------------------------------------
// K4: x_corr = x_n @ kx, *tem, LN, relu, +x_feat. 64-pixel tiles, grid(16,64).
// xtT[n][p] and kc[n][c] padded to 68 -> conflict-free ds_read_b128 inner loop.
// ---------------------------------------------------------------------------
__global__ __launch_bounds__(256) void final_kernel(
    const float* __restrict__ xn, const float* __restrict__ kx,
    const float* __restrict__ tem, const float* __restrict__ xf,
    const float* __restrict__ g, const float* __restrict__ bt,
    float* __restrict__ out)
{
    __shared__ float xtT[64][68];   // [n][p_local]
    __shared__ float kc[64][68];    // [n][c_local]
    __shared__ float rs1[64][17], rs2[64][17];
    __shared__ float mu[64], rr[64];
    const int t = threadIdx.x;
    const int b = blockIdx.y;
    const int pg = blockIdx.x;
    const int tr = t >> 4;          // row group: rows tr*4..tr*4+3
    const int tc = t & 15;          // col group: cols tc*4..tc*4+3 per chunk

    // stage x_n tile transposed
    {
        int row = t >> 2, q = t & 3;
        const float* src = xn + ((long)(b * 1024 + pg * 64 + row)) * 64 + q * 16;
        float4 f0 = *(const float4*)(src + 0);
        float4 f1 = *(const float4*)(src + 4);
        float4 f2 = *(const float4*)(src + 8);
        float4 f3 = *(const float4*)(src + 12);
        int n0 = q * 16;
        xtT[n0 + 0][row] = f0.x; xtT[n0 + 1][row] = f0.y; xtT[n0 + 2][row] = f0.z; xtT[n0 + 3][row] = f0.w;
        xtT[n0 + 4][row] = f1.x; xtT[n0 + 5][row] = f1.y; xtT[n0 + 6][row] = f1.z; xtT[n0 + 7][row] = f1.w;
        xtT[n0 + 8][row] = f2.x; xtT[n0 + 9][row] = f2.y; xtT[n0 +10][row] = f2.z; xtT[n0 +11][row] = f2.w;
        xtT[n0 +12][row] = f3.x; xtT[n0 +13][row] = f3.y; xtT[n0 +14][row] = f3.z; xtT[n0 +15][row] = f3.w;
    }

    float4 xcv[4][4];               // [chunk][row]
    float si[4] = {0.f, 0.f, 0.f, 0.f}, s2i[4] = {0.f, 0.f, 0.f, 0.f};
#pragma unroll
    for (int cc = 0; cc < 4; ++cc) {
        __syncthreads();            // protect kc (and order xtT on first iter)
#pragma unroll
        for (int i = 0; i < 4; ++i) {
            int idx = t + i * 256;
            int n = idx >> 4, jq = idx & 15;
            *(float4*)&kc[n][jq * 4] =
                *(const float4*)(kx + ((long)(b * 64 + n)) * 256 + cc * 64 + jq * 4);
        }
        __syncthreads();
        float4 a0 = {0,0,0,0}, a1 = {0,0,0,0}, a2 = {0,0,0,0}, a3 = {0,0,0,0};
#pragma unroll 8
        for (int n = 0; n < 64; ++n) {
            float4 xv = *(float4*)&xtT[n][tr * 4];
            float4 kv = *(float4*)&kc[n][tc * 4];
            a0.x += xv.x * kv.x; a0.y += xv.x * kv.y; a0.z += xv.x * kv.z; a0.w += xv.x * kv.w;
            a1.x += xv.y * kv.x; a1.y += xv.y * kv.y; a1.z += xv.y * kv.z; a1.w += xv.y * kv.w;
            a2.x += xv.z * kv.x; a2.y += xv.z * kv.y; a2.z += xv.z * kv.z; a2.w += xv.z * kv.w;
            a3.x += xv.w * kv.x; a3.y += xv.w * kv.y; a3.z += xv.w * kv.z; a3.w += xv.w * kv.w;
        }
        float4 tv = *(const float4*)(tem + b * 256 + cc * 64 + tc * 4);
        a0.x *= tv.x; a0.y *= tv.y; a0.z *= tv.z; a0.w *= tv.w;
        a1.x *= tv.x; a1.y *= tv.y; a1.z *= tv.z; a1.w *= tv.w;
        a2.x *= tv.x; a2.y *= tv.y; a2.z *= tv.z; a2.w *= tv.w;
        a3.x *= tv.x; a3.y *= tv.y; a3.z *= tv.z; a3.w *= tv.w;
        xcv[cc][0] = a0; xcv[cc][1] = a1; xcv[cc][2] = a2; xcv[cc][3] = a3;
        si[0]  += a0.x + a0.y + a0.z + a0.w;  s2i[0] += a0.x*a0.x + a0.y*a0.y + a0.z*a0.z + a0.w*a0.w;
        si[1]  += a1.x + a1.y + a1.z + a1.w;  s2i[1] += a1.x*a1.x + a1.y*a1.y + a1.z*a1.z + a1.w*a1.w;
        si[2]  += a2.x + a2.y + a2.z + a2.w;  s2i[2] += a2.x*a2.x + a2.y*a2.y + a2.z*a2.z + a2.w*a2.w;
        si[3]  += a3.x + a3.y + a3.z + a3.w;  s2i[3] += a3.x*a3.x + a3.y*a3.y + a3.z*a3.z + a3.w*a3.w;
    }
#pragma unroll
    for (int i = 0; i < 4; ++i) { rs1[tr * 4 + i][tc] = si[i]; rs2[tr * 4 + i][tc] = s2i[i]; }
    __syncthreads();
    if (t < 64) {
        float s = 0.f, s2 = 0.f;
#pragma unroll
        for (int k = 0; k < 16; ++k) { s += rs1[t][k]; s2 += rs2[t][k]; }
        float m = s * (1.f / 256.f);
        mu[t] = m; rr[t] = rsqrtf(s2 * (1.f / 256.f) - m * m + EPSV);
    }
    __syncthreads();
#pragma unroll
    for (int cc = 0; cc < 4; ++cc) {
        int cb = cc * 64 + tc * 4;
        float4 g4 = *(const float4*)(g + cb);
        float4 b4 = *(const float4*)(bt + cb);
#pragma unroll
        for (int i = 0; i < 4; ++i) {
            int row = tr * 4 + i;
            float m = mu[row], r = rr[row];
            long grow = ((long)(b * 1024 + pg * 64 + row)) * 256;
            float4 xfv = *(const float4*)(xf + grow + cb);
            float4 a = xcv[cc][i];
            float4 o;
            o.x = xfv.x + fmaxf((a.x - m) * r * g4.x + b4.x, 0.f);
            o.y = xfv.y + fmaxf((a.y - m) * r * g4.y + b4.y, 0.f);
            o.z = xfv.z + fmaxf((a.z - m) * r * g4.z + b4.z, 0.f);
            o.w = xfv.w + fmaxf((a.w - m) * r * g4.w + b4.w, 0.f);
            *(float4*)(out + grow + cb) = o;
        }
    }
}

extern "C" void kernel_launch(void* const* d_in, const int* in_sizes, int n_in,
                              void* d_out, int out_size, void* d_ws, size_t ws_size,
                              hipStream_t stream)
{
    (void)in_sizes; (void)n_in; (void)out_size; (void)ws_size;
    const float* x_feat = (const float*)d_in[0];
    const float* z_feat = (const float*)d_in[1];
    const float* Wz     = (const float*)d_in[2];
    const float* bz     = (const float*)d_in[3];
    const float* Wx     = (const float*)d_in[4];
    const float* bx     = (const float*)d_in[5];
    const float* Wdyn   = (const float*)d_in[6];
    const float* bdyn   = (const float*)d_in[7];
    const float* g_norm = (const float*)d_in[8];
    const float* b_norm = (const float*)d_in[9];
    const float* Wp     = (const float*)d_in[10];
    const float* bp     = (const float*)d_in[11];
    const float* g_ln   = (const float*)d_in[12];
    const float* b_ln   = (const float*)d_in[13];
    float* out = (float*)d_out;

    float* ws   = (float*)d_ws;
    float* xn   = ws;                 // 64*1024*64 = 4,194,304
    float* zc   = xn + 4194304;       // 64*256*64  = 1,048,576 (reused as pointbuf)
    float* kern = zc + 1048576;       // 64*64*256  = 1,048,576
    float* kxr  = kern + 1048576;     // 64*64*256  = 1,048,576
    float* kx   = kxr + 1048576;      // 64*64*256  = 1,048,576
    float* temb = kx + 1048576;       // 64*256     =    16,384

    gemm_all<<<1280, 256, 0, stream>>>(x_feat, Wx, bx, xn, z_feat, Wz, bz, zc);
    corr_all<<<dim3(4, 128), 256, 0, stream>>>(xn, x_feat, kxr, zc, z_feat, kern);
    pointln_tem<<<64, 256, 0, stream>>>(kern, Wdyn, bdyn, kxr, g_norm, b_norm,
                                        Wp, bp, /*pointbuf=*/zc, kx, temb);
    final_kernel<<<dim3(16, 64), 256, 0, stream>>>(xn, kx, temb, x_feat, g_ln, b_ln, out);
}